// Round 3
// baseline (1187.108 us; speedup 1.0000x reference)
//
#include <hip/hip_runtime.h>
#include <stdint.h>

// AttentionTrain: out = concat(dec, softmax(dec@enc^T)@enc) per batch.
// B=8, S=2048, H=1024, fp32 in/out.
// Flash-style fused kernel; bf16 hi/lo 3-pass MFMA for scores, bf16 PV.

#define NB 8
#define S 2048
#define H 1024
#define OW 2048
#define BQ 64
#define BE 256
#define BH 32
#define NTILE (S / BE)   // 8
#define NHC (H / BH)     // 32
#define NTHREADS 512

typedef float f32x4 __attribute__((ext_vector_type(4)));
typedef short s16x8 __attribute__((ext_vector_type(8)));
typedef unsigned short u16;
typedef u16 u16x4 __attribute__((ext_vector_type(4)));

__device__ __forceinline__ u16 bf16rne(float x) {
    uint32_t u = __float_as_uint(x);
    return (u16)((u + 0x7FFFu + ((u >> 16) & 1u)) >> 16);
}
__device__ __forceinline__ float bf16f(u16 h) {
    return __uint_as_float(((uint32_t)h) << 16);
}
// LDS tiles with 64-ushort (128 B) rows: XOR-swizzle 16B slots by row&7 -> uniform banks.
__device__ __forceinline__ int swz64(int row, int col) {
    return row * 64 + (col ^ ((row & 7) << 3));
}
// P tile: 256-ushort (512 B) rows, same low-3-slot-bit swizzle.
__device__ __forceinline__ int swzP(int row, int col) {
    return row * 256 + (col ^ ((row & 7) << 3));
}

__global__ __launch_bounds__(NTHREADS) void attn_fused(
    const float* __restrict__ enc, const float* __restrict__ dec,
    float* __restrict__ out)
{
    __shared__ u16 sK[BE * 64];     // 32 KB: K chunk [256][hi32|lo32]; aliased by P[64][256] in PV
    __shared__ u16 sQ[BQ * 64];     // 8 KB:  Q chunk [64][hi32|lo32]
    __shared__ float wred[8 * 64];  // cross-wave partials (max, then sum)
    __shared__ float mlds[64], llds[64], alds[64];

    const int bid = blockIdx.x;
    const int b   = bid & 7;        // batch -> XCD affinity
    const int qt  = bid >> 3;
    const int q0  = qt * BQ;
    const int tid = (int)threadIdx.x;
    const int lane = tid & 63;
    const int wid  = tid >> 6;
    const int rl = lane & 15;       // frag row/col lane index
    const int rg = lane >> 4;       // frag k-group

    const float* __restrict__ encB = enc + (size_t)b * S * H;
    const float* __restrict__ decB = dec + (size_t)b * S * H;
    float* __restrict__ outB = out + (size_t)b * S * OW;

    // ---- exact copy of dec rows into left half of out ----
    #pragma unroll 4
    for (int i = 0; i < 32; ++i) {
        int u = tid + i * NTHREADS;       // 64 rows x 256 float4
        int row = u >> 8;
        int c4 = (u & 255) << 2;
        f32x4 v = *(const f32x4*)&decB[(size_t)(q0 + row) * H + c4];
        *(f32x4*)&outB[(size_t)(q0 + row) * OW + c4] = v;
    }

    if (tid < 64) { mlds[tid] = -3.0e38f; llds[tid] = 0.0f; alds[tid] = 0.0f; }

    // ctx accumulator: wave owns [64 q][128 h] as 4x8 16x16 frags
    f32x4 ctx[4][8];
    #pragma unroll
    for (int mi = 0; mi < 4; ++mi)
        #pragma unroll
        for (int ni = 0; ni < 8; ++ni)
            ctx[mi][ni] = f32x4{0.f, 0.f, 0.f, 0.f};

    __syncthreads();

    for (int et = 0; et < NTILE; ++et) {
        const int e0 = et * BE;

        // ---- phase A: S^T[256 e][64 q] = K·Q^T, 3-pass bf16 hi/lo ----
        // wave wid owns e-slice [wid*32, wid*32+32): frags mi(2, e) x ni(4, q)
        f32x4 accs[2][4];
        #pragma unroll
        for (int mi = 0; mi < 2; ++mi)
            #pragma unroll
            for (int ni = 0; ni < 4; ++ni)
                accs[mi][ni] = f32x4{0.f, 0.f, 0.f, 0.f};

        for (int hc = 0; hc < NHC; ++hc) {
            const int h0 = hc * BH;
            // stage K chunk: 256 rows x 32 h (fp32 -> bf16 hi/lo)
            #pragma unroll
            for (int i = 0; i < 4; ++i) {
                int u = tid + i * NTHREADS;   // 256 rows x 8 col-quads
                int row = u >> 3;
                int cq = (u & 7) << 2;
                f32x4 v = *(const f32x4*)&encB[(size_t)(e0 + row) * H + h0 + cq];
                u16x4 hi, lo;
                #pragma unroll
                for (int j = 0; j < 4; ++j) {
                    u16 hh = bf16rne(v[j]);
                    hi[j] = hh;
                    lo[j] = bf16rne(v[j] - bf16f(hh));
                }
                *(u16x4*)&sK[swz64(row, cq)]      = hi;
                *(u16x4*)&sK[swz64(row, cq + 32)] = lo;
            }
            // stage Q chunk: 64 rows x 32 h
            {
                int row = tid >> 3;
                int cq = (tid & 7) << 2;
                f32x4 v = *(const f32x4*)&decB[(size_t)(q0 + row) * H + h0 + cq];
                u16x4 hi, lo;
                #pragma unroll
                for (int j = 0; j < 4; ++j) {
                    u16 hh = bf16rne(v[j]);
                    hi[j] = hh;
                    lo[j] = bf16rne(v[j] - bf16f(hh));
                }
                *(u16x4*)&sQ[swz64(row, cq)]      = hi;
                *(u16x4*)&sQ[swz64(row, cq + 32)] = lo;
            }
            __syncthreads();

            s16x8 ka[2], kl[2];
            #pragma unroll
            for (int mi = 0; mi < 2; ++mi) {
                int row = wid * 32 + mi * 16 + rl;
                ka[mi] = *(const s16x8*)&sK[swz64(row, rg * 8)];
                kl[mi] = *(const s16x8*)&sK[swz64(row, rg * 8 + 32)];
            }
            s16x8 qa[4], ql[4];
            #pragma unroll
            for (int ni = 0; ni < 4; ++ni) {
                int row = ni * 16 + rl;
                qa[ni] = *(const s16x8*)&sQ[swz64(row, rg * 8)];
                ql[ni] = *(const s16x8*)&sQ[swz64(row, rg * 8 + 32)];
            }
            #pragma unroll
            for (int mi = 0; mi < 2; ++mi)
                #pragma unroll
                for (int ni = 0; ni < 4; ++ni) {
                    f32x4 c = accs[mi][ni];
                    c = __builtin_amdgcn_mfma_f32_16x16x32_bf16(ka[mi], qa[ni], c, 0, 0, 0);
                    c = __builtin_amdgcn_mfma_f32_16x16x32_bf16(ka[mi], ql[ni], c, 0, 0, 0);
                    c = __builtin_amdgcn_mfma_f32_16x16x32_bf16(kl[mi], qa[ni], c, 0, 0, 0);
                    accs[mi][ni] = c;
                }
            __syncthreads();
        }

        // ---- online softmax over this E-tile (per q column of S^T) ----
        float tmax[4];
        #pragma unroll
        for (int ni = 0; ni < 4; ++ni) {
            float t = accs[0][ni][0];
            #pragma unroll
            for (int mi = 0; mi < 2; ++mi)
                #pragma unroll
                for (int r = 0; r < 4; ++r)
                    t = fmaxf(t, accs[mi][ni][r]);
            t = fmaxf(t, __shfl_xor(t, 16));
            t = fmaxf(t, __shfl_xor(t, 32));
            tmax[ni] = t;
        }
        // lane l carries q = l (ni = rg): one write per lane
        float tsel = rg == 0 ? tmax[0] : rg == 1 ? tmax[1] : rg == 2 ? tmax[2] : tmax[3];
        wred[wid * 64 + lane] = tsel;
        __syncthreads();
        if (wid == 0) {
            float t = wred[lane];
            #pragma unroll
            for (int w = 1; w < 8; ++w) t = fmaxf(t, wred[w * 64 + lane]);
            float mo = mlds[lane];
            float mn = fmaxf(mo, t);
            mlds[lane] = mn;
            alds[lane] = __expf(mo - mn);
        }
        __syncthreads();

        // P = exp(S - m) -> bf16 into sP (aliases sK); per-column sums; ctx rescale
        float mq[4];
        #pragma unroll
        for (int ni = 0; ni < 4; ++ni) mq[ni] = mlds[ni * 16 + rl];

        u16* sP = sK;
        float tsum[4] = {0.f, 0.f, 0.f, 0.f};
        #pragma unroll
        for (int mi = 0; mi < 2; ++mi)
            #pragma unroll
            for (int ni = 0; ni < 4; ++ni) {
                u16x4 pk;
                #pragma unroll
                for (int r = 0; r < 4; ++r) {
                    float p = __expf(accs[mi][ni][r] - mq[ni]);
                    tsum[ni] += p;
                    pk[r] = bf16rne(p);
                }
                // e-col within tile = wid*32 + mi*16 + rg*4 + r; q row = ni*16+rl
                *(u16x4*)&sP[swzP(ni * 16 + rl, wid * 32 + mi * 16 + rg * 4)] = pk;
            }
        #pragma unroll
        for (int ni = 0; ni < 4; ++ni) {
            tsum[ni] += __shfl_xor(tsum[ni], 16);
            tsum[ni] += __shfl_xor(tsum[ni], 32);
        }
        float ssel = rg == 0 ? tsum[0] : rg == 1 ? tsum[1] : rg == 2 ? tsum[2] : tsum[3];
        wred[wid * 64 + lane] = ssel;

        // rescale ctx by alpha[q]
        #pragma unroll
        for (int mi = 0; mi < 4; ++mi) {
            f32x4 a = *(const f32x4*)&alds[mi * 16 + rg * 4];
            #pragma unroll
            for (int ni = 0; ni < 8; ++ni)
                #pragma unroll
                for (int r = 0; r < 4; ++r)
                    ctx[mi][ni][r] *= a[r];
        }
        __syncthreads();   // P + sums visible
        if (wid == 0) {
            float t = 0.f;
            #pragma unroll
            for (int w = 0; w < 8; ++w) t += wred[w * 64 + lane];
            llds[lane] = llds[lane] * alds[lane] + t;
        }

        // ---- PV: ctx[64 q][wave's 128 h] += P[64][256] · V[256][h] ----
        const int wh0 = wid * 128;
        for (int ks = 0; ks < 8; ++ks) {
            s16x8 pa[4];
            #pragma unroll
            for (int mi = 0; mi < 4; ++mi)
                pa[mi] = *(const s16x8*)&sP[swzP(mi * 16 + rl, ks * 32 + rg * 8)];
            #pragma unroll
            for (int ni = 0; ni < 8; ++ni) {
                const float* vp = &encB[(size_t)(e0 + ks * 32 + rg * 8) * H + wh0 + ni * 16 + rl];
                float bv[8];
                #pragma unroll
                for (int j = 0; j < 8; ++j) bv[j] = vp[(size_t)j * H];
                s16x8 bb;
                #pragma unroll
                for (int j = 0; j < 8; ++j) bb[j] = (short)bf16rne(bv[j]);
                #pragma unroll
                for (int mi = 0; mi < 4; ++mi)
                    ctx[mi][ni] = __builtin_amdgcn_mfma_f32_16x16x32_bf16(pa[mi], bb, ctx[mi][ni], 0, 0, 0);
            }
        }
        __syncthreads();   // protect sP/sK before next tile's staging
    }

    // ---- epilogue: ctx / l -> right half of out ----
    #pragma unroll
    for (int mi = 0; mi < 4; ++mi) {
        f32x4 lv = *(const f32x4*)&llds[mi * 16 + rg * 4];
        f32x4 inv;
        #pragma unroll
        for (int r = 0; r < 4; ++r) inv[r] = 1.0f / lv[r];
        #pragma unroll
        for (int ni = 0; ni < 8; ++ni) {
            int hcol = wid * 128 + ni * 16 + rl;
            #pragma unroll
            for (int r = 0; r < 4; ++r) {
                int qrow = q0 + mi * 16 + rg * 4 + r;
                outB[(size_t)qrow * OW + H + hcol] = ctx[mi][ni][r] * inv[r];
            }
        }
    }
}

extern "C" void kernel_launch(void* const* d_in, const int* in_sizes, int n_in,
                              void* d_out, int out_size, void* d_ws, size_t ws_size,
                              hipStream_t stream) {
    const float* enc = (const float*)d_in[0];
    const float* dec = (const float*)d_in[1];
    float* out = (float*)d_out;
    attn_fused<<<dim3(NB * (S / BQ)), dim3(NTHREADS), 0, stream>>>(enc, dec, out);
}

// Round 4
// 913.706 us; speedup vs baseline: 1.2992x; 1.2992x over previous
//
#include <hip/hip_runtime.h>
#include <stdint.h>

// AttentionTrain: out = concat(dec, softmax(dec@enc^T)@enc) per batch.
// B=8, S=2048, H=1024, fp32 in/out.
// v2: BQ=32 (512 blocks, 2/CU), ws-preconverted bf16 hi/lo tiles staged via
// global_load_lds, double-buffered K/Q (1 barrier per hc).
// Fallback (ws too small): round-3 validated kernel.

typedef float f32x4 __attribute__((ext_vector_type(4)));
typedef short s16x8 __attribute__((ext_vector_type(8)));
typedef unsigned short u16;
typedef u16 u16x4 __attribute__((ext_vector_type(4)));
typedef u16 u16x8 __attribute__((ext_vector_type(8)));

__device__ __forceinline__ u16 bf16rne(float x) {
    uint32_t u = __float_as_uint(x);
    return (u16)((u + 0x7FFFu + ((u >> 16) & 1u)) >> 16);
}
__device__ __forceinline__ float bf16f(u16 h) {
    return __uint_as_float(((uint32_t)h) << 16);
}
// rows of 64 u16 (128 B): XOR-swizzle 8-u16 (16B) granules by row&7.
__device__ __forceinline__ int swz64(int row, int col) {
    return row * 64 + (col ^ ((row & 7) << 3));
}
// P tile rows of 256 u16 (512 B), same granule swizzle.
__device__ __forceinline__ int swzP(int row, int col) {
    return row * 256 + (col ^ ((row & 7) << 3));
}

// ---------------- prep kernels: fp32 -> bf16 hi/lo swizzled tile images ----
// wsK image: [b][et(8)][hc(32)][r(256)][g(8)] 16B granules; granule g of row r
// holds logical granule cl = g ^ (r&7); cl<4 -> hi of h-cols [8cl,8cl+8),
// cl>=4 -> lo of h-cols [8(cl-4),...). (matches swz64 reads)
__global__ __launch_bounds__(256) void encprep(const float* __restrict__ enc,
                                               u16* __restrict__ wsK) {
    int gid = blockIdx.x * 256 + (int)threadIdx.x;   // 4,194,304 granules
    int g  = gid & 7;
    int r  = (gid >> 3) & 255;
    int hc = (gid >> 11) & 31;
    int et = (gid >> 16) & 7;
    int b  = gid >> 19;
    int cl = g ^ (r & 7);
    int lo = cl >> 2;
    int c0 = (cl & 3) * 8;
    const float* src = enc + ((size_t)((b * 8 + et) * 256 + r) * 1024) + hc * 32 + c0;
    f32x4 v0 = *(const f32x4*)src;
    f32x4 v1 = *(const f32x4*)(src + 4);
    u16x8 o;
    #pragma unroll
    for (int j = 0; j < 4; ++j) {
        u16 h0 = bf16rne(v0[j]);
        u16 h1 = bf16rne(v1[j]);
        o[j]     = lo ? bf16rne(v0[j] - bf16f(h0)) : h0;
        o[4 + j] = lo ? bf16rne(v1[j] - bf16f(h1)) : h1;
    }
    *(u16x8*)(wsK + (size_t)gid * 8) = o;
}

// wsQ image: [b][qt(64)][hc(32)][r(32)][g(8)] granules, same convention.
__global__ __launch_bounds__(256) void decprep(const float* __restrict__ dec,
                                               u16* __restrict__ wsQ) {
    int gid = blockIdx.x * 256 + (int)threadIdx.x;   // 4,194,304 granules
    int g  = gid & 7;
    int r  = (gid >> 3) & 31;
    int hc = (gid >> 8) & 31;
    int qt = (gid >> 13) & 63;
    int b  = gid >> 19;
    int cl = g ^ (r & 7);
    int lo = cl >> 2;
    int c0 = (cl & 3) * 8;
    const float* src = dec + ((size_t)((b * 64 + qt) * 32 + r) * 1024) + hc * 32 + c0;
    f32x4 v0 = *(const f32x4*)src;
    f32x4 v1 = *(const f32x4*)(src + 4);
    u16x8 o;
    #pragma unroll
    for (int j = 0; j < 4; ++j) {
        u16 h0 = bf16rne(v0[j]);
        u16 h1 = bf16rne(v1[j]);
        o[j]     = lo ? bf16rne(v0[j] - bf16f(h0)) : h0;
        o[4 + j] = lo ? bf16rne(v1[j] - bf16f(h1)) : h1;
    }
    *(u16x8*)(wsQ + (size_t)gid * 8) = o;
}

// ---------------- main kernel v2 ----------------
__device__ __forceinline__ void stage_tiles(const u16* kt, const u16* qt_,
                                            u16* sKb, u16* sQb, int wid, int lane) {
    // K: 2048 granules = 8 waves x 64 lanes x 4 issues of 16B
    #pragma unroll
    for (int i = 0; i < 4; ++i) {
        int idx = i * 512 + wid * 64;      // lane*16 added by HW on LDS side
        __builtin_amdgcn_global_load_lds(
            (const __attribute__((address_space(1))) void*)(kt + (size_t)(idx + lane) * 8),
            (__attribute__((address_space(3))) void*)(sKb + (size_t)idx * 8),
            16, 0, 0);
    }
    // Q: 256 granules = waves 0-3 x 64 lanes x 16B
    if (wid < 4) {
        int idx = wid * 64;
        __builtin_amdgcn_global_load_lds(
            (const __attribute__((address_space(1))) void*)(qt_ + (size_t)(idx + lane) * 8),
            (__attribute__((address_space(3))) void*)(sQb + (size_t)idx * 8),
            16, 0, 0);
    }
}

__global__ __launch_bounds__(512, 4) void attn_v2(
    const float* __restrict__ enc, const float* __restrict__ dec,
    const u16* __restrict__ wsK, const u16* __restrict__ wsQ,
    float* __restrict__ out)
{
    __shared__ u16 sK[2][256 * 64];   // 2 x 32 KB double-buffered K hi|lo image
    __shared__ u16 sQ[2][32 * 64];    // 2 x 4 KB  double-buffered Q hi|lo image
    __shared__ __align__(16) float wred[8 * 32];
    __shared__ __align__(16) float mlds[32], llds[32], alds[32];

    const int bid = blockIdx.x;
    const int b   = bid & 7;          // batch -> XCD affinity
    const int qt  = bid >> 3;         // 0..63
    const int q0  = qt * 32;
    const int tid = (int)threadIdx.x;
    const int lane = tid & 63;
    const int wid  = tid >> 6;
    const int rl = lane & 15;
    const int rg = lane >> 4;

    const float* __restrict__ encB = enc + (size_t)b * 2048 * 1024;
    const float* __restrict__ decB = dec + (size_t)b * 2048 * 1024;
    float* __restrict__ outB = out + (size_t)b * 2048 * 2048;
    const u16* ktb = wsK + (size_t)b * 4194304;                 // [et][hc] tiles
    const u16* qtb = wsQ + (size_t)(b * 64 + qt) * 65536;       // [hc] tiles

    // ---- exact copy of dec rows into left half of out ----
    #pragma unroll
    for (int i = 0; i < 16; ++i) {
        int u = tid + i * 512;            // 32 rows x 256 float4
        int row = u >> 8;
        int c4 = (u & 255) << 2;
        f32x4 v = *(const f32x4*)&decB[(size_t)(q0 + row) * 1024 + c4];
        *(f32x4*)&outB[(size_t)(q0 + row) * 2048 + c4] = v;
    }

    if (tid < 32) { mlds[tid] = -3.0e38f; llds[tid] = 0.f; alds[tid] = 0.f; }

    f32x4 ctx[2][8];
    #pragma unroll
    for (int mi = 0; mi < 2; ++mi)
        #pragma unroll
        for (int ni = 0; ni < 8; ++ni)
            ctx[mi][ni] = f32x4{0.f, 0.f, 0.f, 0.f};

    __syncthreads();

    for (int et = 0; et < 8; ++et) {
        const int e0 = et * 256;
        const u16* kt_et = ktb + (size_t)et * 524288;

        f32x4 accs[2][2];
        #pragma unroll
        for (int mi = 0; mi < 2; ++mi)
            #pragma unroll
            for (int ni = 0; ni < 2; ++ni)
                accs[mi][ni] = f32x4{0.f, 0.f, 0.f, 0.f};

        // prologue: stage hc=0 into buf0 (barrier drains vmcnt)
        stage_tiles(kt_et, qtb, sK[0], sQ[0], wid, lane);
        __syncthreads();

        for (int hc = 0; hc < 32; ++hc) {
            const int cb = hc & 1;
            if (hc + 1 < 32)
                stage_tiles(kt_et + (size_t)(hc + 1) * 16384,
                            qtb + (size_t)(hc + 1) * 2048,
                            sK[cb ^ 1], sQ[cb ^ 1], wid, lane);

            const u16* sKb = sK[cb];
            const u16* sQb = sQ[cb];
            s16x8 ka[2], kl[2], qa[2], ql[2];
            #pragma unroll
            for (int mi = 0; mi < 2; ++mi) {
                int row = wid * 32 + mi * 16 + rl;
                ka[mi] = *(const s16x8*)&sKb[swz64(row, rg * 8)];
                kl[mi] = *(const s16x8*)&sKb[swz64(row, rg * 8 + 32)];
            }
            #pragma unroll
            for (int ni = 0; ni < 2; ++ni) {
                int row = ni * 16 + rl;
                qa[ni] = *(const s16x8*)&sQb[swz64(row, rg * 8)];
                ql[ni] = *(const s16x8*)&sQb[swz64(row, rg * 8 + 32)];
            }
            #pragma unroll
            for (int mi = 0; mi < 2; ++mi)
                #pragma unroll
                for (int ni = 0; ni < 2; ++ni) {
                    f32x4 c = accs[mi][ni];
                    c = __builtin_amdgcn_mfma_f32_16x16x32_bf16(ka[mi], qa[ni], c, 0, 0, 0);
                    c = __builtin_amdgcn_mfma_f32_16x16x32_bf16(ka[mi], ql[ni], c, 0, 0, 0);
                    c = __builtin_amdgcn_mfma_f32_16x16x32_bf16(kl[mi], qa[ni], c, 0, 0, 0);
                    accs[mi][ni] = c;
                }
            __syncthreads();   // next buffer staged + all reads of cb done
        }

        // ---- online softmax over this E-tile (S^T: lane holds q=ni*16+rl) ----
        float tmax[2];
        #pragma unroll
        for (int ni = 0; ni < 2; ++ni) {
            float t = -3.0e38f;
            #pragma unroll
            for (int mi = 0; mi < 2; ++mi)
                #pragma unroll
                for (int r = 0; r < 4; ++r)
                    t = fmaxf(t, accs[mi][ni][r]);
            t = fmaxf(t, __shfl_xor(t, 16));
            t = fmaxf(t, __shfl_xor(t, 32));
            tmax[ni] = t;
        }
        if (rg < 2) wred[wid * 32 + (lane & 31)] = (rg == 0) ? tmax[0] : tmax[1];
        __syncthreads();
        if (tid < 32) {
            float t = wred[tid];
            #pragma unroll
            for (int w = 1; w < 8; ++w) t = fmaxf(t, wred[w * 32 + tid]);
            float mo = mlds[tid];
            float mn = fmaxf(mo, t);
            mlds[tid] = mn;
            alds[tid] = __expf(mo - mn);
        }
        __syncthreads();

        float mq[2] = { mlds[rl], mlds[16 + rl] };

        u16* sP = sK[0];   // 32x256 u16 = 16 KB alias (buf0 reads all done)
        float tsum[2] = {0.f, 0.f};
        #pragma unroll
        for (int mi = 0; mi < 2; ++mi)
            #pragma unroll
            for (int ni = 0; ni < 2; ++ni) {
                u16x4 pk;
                #pragma unroll
                for (int r = 0; r < 4; ++r) {
                    float p = __expf(accs[mi][ni][r] - mq[ni]);
                    tsum[ni] += p;
                    pk[r] = bf16rne(p);
                }
                *(u16x4*)&sP[swzP(ni * 16 + rl, wid * 32 + mi * 16 + rg * 4)] = pk;
            }
        #pragma unroll
        for (int ni = 0; ni < 2; ++ni) {
            tsum[ni] += __shfl_xor(tsum[ni], 16);
            tsum[ni] += __shfl_xor(tsum[ni], 32);
        }
        if (rg < 2) wred[wid * 32 + (lane & 31)] = (rg == 0) ? tsum[0] : tsum[1];

        // rescale ctx by alpha[q] (q = mi*16 + rg*4 + r)
        #pragma unroll
        for (int mi = 0; mi < 2; ++mi) {
            f32x4 a = *(const f32x4*)&alds[mi * 16 + rg * 4];
            #pragma unroll
            for (int ni = 0; ni < 8; ++ni)
                #pragma unroll
                for (int r = 0; r < 4; ++r)
                    ctx[mi][ni][r] *= a[r];
        }
        __syncthreads();   // sP + sum partials visible
        if (tid < 32) {
            float t = 0.f;
            #pragma unroll
            for (int w = 0; w < 8; ++w) t += wred[w * 32 + tid];
            llds[tid] = llds[tid] * alds[tid] + t;
        }

        // ---- PV: ctx[32 q][wave's 128 h] += P[32][256] . V[256][h] ----
        const int wh0 = wid * 128;
        for (int ks = 0; ks < 8; ++ks) {
            s16x8 pa[2];
            #pragma unroll
            for (int mi = 0; mi < 2; ++mi)
                pa[mi] = *(const s16x8*)&sP[swzP(mi * 16 + rl, ks * 32 + rg * 8)];
            #pragma unroll
            for (int ni = 0; ni < 8; ++ni) {
                const float* vp = &encB[(size_t)(e0 + ks * 32 + rg * 8) * 1024 + wh0 + ni * 16 + rl];
                s16x8 bb;
                #pragma unroll
                for (int j = 0; j < 8; ++j) bb[j] = (short)bf16rne(vp[(size_t)j * 1024]);
                #pragma unroll
                for (int mi = 0; mi < 2; ++mi)
                    ctx[mi][ni] = __builtin_amdgcn_mfma_f32_16x16x32_bf16(pa[mi], bb, ctx[mi][ni], 0, 0, 0);
            }
        }
        __syncthreads();   // protect sP before next tile's staging into buf0
    }

    // ---- epilogue: ctx / l -> right half of out ----
    #pragma unroll
    for (int mi = 0; mi < 2; ++mi) {
        f32x4 lv = *(const f32x4*)&llds[mi * 16 + rg * 4];
        f32x4 inv;
        #pragma unroll
        for (int r = 0; r < 4; ++r) inv[r] = 1.0f / lv[r];
        #pragma unroll
        for (int ni = 0; ni < 8; ++ni) {
            int hcol = wid * 128 + ni * 16 + rl;
            #pragma unroll
            for (int r = 0; r < 4; ++r) {
                int qrow = q0 + mi * 16 + rg * 4 + r;
                outB[(size_t)qrow * 2048 + 1024 + hcol] = ctx[mi][ni][r] * inv[r];
            }
        }
    }
}

// ---------------- round-3 validated fallback (ws too small) ----------------
#define NB 8
#define S 2048
#define H 1024
#define OW 2048
#define BQ 64
#define BE 256
#define BH 32
#define NTILE (S / BE)
#define NHC (H / BH)
#define NTHREADS 512

__global__ __launch_bounds__(NTHREADS) void attn_fused(
    const float* __restrict__ enc, const float* __restrict__ dec,
    float* __restrict__ out)
{
    __shared__ u16 sK[BE * 64];
    __shared__ u16 sQ[BQ * 64];
    __shared__ float wred[8 * 64];
    __shared__ float mlds[64], llds[64], alds[64];

    const int bid = blockIdx.x;
    const int b   = bid & 7;
    const int qt  = bid >> 3;
    const int q0  = qt * BQ;
    const int tid = (int)threadIdx.x;
    const int lane = tid & 63;
    const int wid  = tid >> 6;
    const int rl = lane & 15;
    const int rg = lane >> 4;

    const float* __restrict__ encB = enc + (size_t)b * S * H;
    const float* __restrict__ decB = dec + (size_t)b * S * H;
    float* __restrict__ outB = out + (size_t)b * S * OW;

    #pragma unroll 4
    for (int i = 0; i < 32; ++i) {
        int u = tid + i * NTHREADS;
        int row = u >> 8;
        int c4 = (u & 255) << 2;
        f32x4 v = *(const f32x4*)&decB[(size_t)(q0 + row) * H + c4];
        *(f32x4*)&outB[(size_t)(q0 + row) * OW + c4] = v;
    }

    if (tid < 64) { mlds[tid] = -3.0e38f; llds[tid] = 0.0f; alds[tid] = 0.0f; }

    f32x4 ctx[4][8];
    #pragma unroll
    for (int mi = 0; mi < 4; ++mi)
        #pragma unroll
        for (int ni = 0; ni < 8; ++ni)
            ctx[mi][ni] = f32x4{0.f, 0.f, 0.f, 0.f};

    __syncthreads();

    for (int et = 0; et < NTILE; ++et) {
        const int e0 = et * BE;
        f32x4 accs[2][4];
        #pragma unroll
        for (int mi = 0; mi < 2; ++mi)
            #pragma unroll
            for (int ni = 0; ni < 4; ++ni)
                accs[mi][ni] = f32x4{0.f, 0.f, 0.f, 0.f};

        for (int hc = 0; hc < NHC; ++hc) {
            const int h0 = hc * BH;
            #pragma unroll
            for (int i = 0; i < 4; ++i) {
                int u = tid + i * NTHREADS;
                int row = u >> 3;
                int cq = (u & 7) << 2;
                f32x4 v = *(const f32x4*)&encB[(size_t)(e0 + row) * H + h0 + cq];
                u16x4 hi, lo;
                #pragma unroll
                for (int j = 0; j < 4; ++j) {
                    u16 hh = bf16rne(v[j]);
                    hi[j] = hh;
                    lo[j] = bf16rne(v[j] - bf16f(hh));
                }
                *(u16x4*)&sK[swz64(row, cq)]      = hi;
                *(u16x4*)&sK[swz64(row, cq + 32)] = lo;
            }
            {
                int row = tid >> 3;
                int cq = (tid & 7) << 2;
                f32x4 v = *(const f32x4*)&decB[(size_t)(q0 + row) * H + h0 + cq];
                u16x4 hi, lo;
                #pragma unroll
                for (int j = 0; j < 4; ++j) {
                    u16 hh = bf16rne(v[j]);
                    hi[j] = hh;
                    lo[j] = bf16rne(v[j] - bf16f(hh));
                }
                *(u16x4*)&sQ[swz64(row, cq)]      = hi;
                *(u16x4*)&sQ[swz64(row, cq + 32)] = lo;
            }
            __syncthreads();

            s16x8 ka[2], kl[2];
            #pragma unroll
            for (int mi = 0; mi < 2; ++mi) {
                int row = wid * 32 + mi * 16 + rl;
                ka[mi] = *(const s16x8*)&sK[swz64(row, rg * 8)];
                kl[mi] = *(const s16x8*)&sK[swz64(row, rg * 8 + 32)];
            }
            s16x8 qa[4], ql[4];
            #pragma unroll
            for (int ni = 0; ni < 4; ++ni) {
                int row = ni * 16 + rl;
                qa[ni] = *(const s16x8*)&sQ[swz64(row, rg * 8)];
                ql[ni] = *(const s16x8*)&sQ[swz64(row, rg * 8 + 32)];
            }
            #pragma unroll
            for (int mi = 0; mi < 2; ++mi)
                #pragma unroll
                for (int ni = 0; ni < 4; ++ni) {
                    f32x4 c = accs[mi][ni];
                    c = __builtin_amdgcn_mfma_f32_16x16x32_bf16(ka[mi], qa[ni], c, 0, 0, 0);
                    c = __builtin_amdgcn_mfma_f32_16x16x32_bf16(ka[mi], ql[ni], c, 0, 0, 0);
                    c = __builtin_amdgcn_mfma_f32_16x16x32_bf16(kl[mi], qa[ni], c, 0, 0, 0);
                    accs[mi][ni] = c;
                }
            __syncthreads();
        }

        float tmax[4];
        #pragma unroll
        for (int ni = 0; ni < 4; ++ni) {
            float t = accs[0][ni][0];
            #pragma unroll
            for (int mi = 0; mi < 2; ++mi)
                #pragma unroll
                for (int r = 0; r < 4; ++r)
                    t = fmaxf(t, accs[mi][ni][r]);
            t = fmaxf(t, __shfl_xor(t, 16));
            t = fmaxf(t, __shfl_xor(t, 32));
            tmax[ni] = t;
        }
        float tsel = rg == 0 ? tmax[0] : rg == 1 ? tmax[1] : rg == 2 ? tmax[2] : tmax[3];
        wred[wid * 64 + lane] = tsel;
        __syncthreads();
        if (wid == 0) {
            float t = wred[lane];
            #pragma unroll
            for (int w = 1; w < 8; ++w) t = fmaxf(t, wred[w * 64 + lane]);
            float mo = mlds[lane];
            float mn = fmaxf(mo, t);
            mlds[lane] = mn;
            alds[lane] = __expf(mo - mn);
        }
        __syncthreads();

        float mq[4];
        #pragma unroll
        for (int ni = 0; ni < 4; ++ni) mq[ni] = mlds[ni * 16 + rl];

        u16* sP = sK;
        float tsum[4] = {0.f, 0.f, 0.f, 0.f};
        #pragma unroll
        for (int mi = 0; mi < 2; ++mi)
            #pragma unroll
            for (int ni = 0; ni < 4; ++ni) {
                u16x4 pk;
                #pragma unroll
                for (int r = 0; r < 4; ++r) {
                    float p = __expf(accs[mi][ni][r] - mq[ni]);
                    tsum[ni] += p;
                    pk[r] = bf16rne(p);
                }
                *(u16x4*)&sP[swzP(ni * 16 + rl, wid * 32 + mi * 16 + rg * 4)] = pk;
            }
        #pragma unroll
        for (int ni = 0; ni < 4; ++ni) {
            tsum[ni] += __shfl_xor(tsum[ni], 16);
            tsum[ni] += __shfl_xor(tsum[ni], 32);
        }
        float ssel = rg == 0 ? tsum[0] : rg == 1 ? tsum[1] : rg == 2 ? tsum[2] : tsum[3];
        wred[wid * 64 + lane] = ssel;

        #pragma unroll
        for (int mi = 0; mi < 4; ++mi) {
            f32x4 a = *(const f32x4*)&alds[mi * 16 + rg * 4];
            #pragma unroll
            for (int ni = 0; ni < 8; ++ni)
                #pragma unroll
                for (int r = 0; r < 4; ++r)
                    ctx[mi][ni][r] *= a[r];
        }
        __syncthreads();
        if (wid == 0) {
            float t = 0.f;
            #pragma unroll
            for (int w = 0; w < 8; ++w) t += wred[w * 64 + lane];
            llds[lane] = llds[lane] * alds[lane] + t;
        }

        const int wh0 = wid * 128;
        for (int ks = 0; ks < 8; ++ks) {
            s16x8 pa[4];
            #pragma unroll
            for (int mi = 0; mi < 4; ++mi)
                pa[mi] = *(const s16x8*)&sP[swzP(mi * 16 + rl, ks * 32 + rg * 8)];
            #pragma unroll
            for (int ni = 0; ni < 8; ++ni) {
                const float* vp = &encB[(size_t)(e0 + ks * 32 + rg * 8) * H + wh0 + ni * 16 + rl];
                float bv[8];
                #pragma unroll
                for (int j = 0; j < 8; ++j) bv[j] = vp[(size_t)j * H];
                s16x8 bb;
                #pragma unroll
                for (int j = 0; j < 8; ++j) bb[j] = (short)bf16rne(bv[j]);
                #pragma unroll
                for (int mi = 0; mi < 4; ++mi)
                    ctx[mi][ni] = __builtin_amdgcn_mfma_f32_16x16x32_bf16(pa[mi], bb, ctx[mi][ni], 0, 0, 0);
            }
        }
        __syncthreads();
    }

    #pragma unroll
    for (int mi = 0; mi < 4; ++mi) {
        f32x4 lv = *(const f32x4*)&llds[mi * 16 + rg * 4];
        f32x4 inv;
        #pragma unroll
        for (int r = 0; r < 4; ++r) inv[r] = 1.0f / lv[r];
        #pragma unroll
        for (int ni = 0; ni < 8; ++ni) {
            int hcol = wid * 128 + ni * 16 + rl;
            #pragma unroll
            for (int r = 0; r < 4; ++r) {
                int qrow = q0 + mi * 16 + rg * 4 + r;
                outB[(size_t)qrow * OW + H + hcol] = ctx[mi][ni][r] * inv[r];
            }
        }
    }
}

extern "C" void kernel_launch(void* const* d_in, const int* in_sizes, int n_in,
                              void* d_out, int out_size, void* d_ws, size_t ws_size,
                              hipStream_t stream) {
    (void)in_sizes; (void)n_in; (void)out_size;
    const float* enc = (const float*)d_in[0];
    const float* dec = (const float*)d_in[1];
    float* out = (float*)d_out;
    const size_t NEED = 134217728ull;   // 64 MiB enc-image + 64 MiB dec-image
    if (ws_size >= NEED) {
        u16* wsK = (u16*)d_ws;
        u16* wsQ = wsK + 33554432ull;
        encprep<<<dim3(16384), dim3(256), 0, stream>>>(enc, wsK);
        decprep<<<dim3(16384), dim3(256), 0, stream>>>(dec, wsQ);
        attn_v2<<<dim3(512), dim3(512), 0, stream>>>(enc, dec, wsK, wsQ, out);
    } else {
        attn_fused<<<dim3(256), dim3(512), 0, stream>>>(enc, dec, out);
    }
}